// Round 6
// baseline (26.043 us; speedup 1.0000x reference)
//
#include <hip/hip_runtime.h>
#include <math.h>

#define HEADS 4
#define CDIM 128
#define HDIM 512       // HEADS*CDIM
#define FEAT 128
#define NBS 128        // scan blocks; block NBS is the dedicated target block
#define NT 512
#define REG 8          // per-block slot region (window in-degree ~0.06)
#define TGT_SID (NBS * REG)
#define NMAX 64        // max softmax slots in finalize (incl. self-loop)

// ---------------- zero the done counter ----------------
__global__ void zero_kernel(int* __restrict__ p) {
    if (threadIdx.x == 0) p[0] = 0;
}

// ---------------- mega: scan + node pipelines + last-block finalize ----------------
__global__ __launch_bounds__(NT)
void mega_kernel(const float* __restrict__ des, const float* __restrict__ tw,
                 const float* __restrict__ npr, const float* __restrict__ cpr,
                 const float* __restrict__ Wd, const float* __restrict__ bd,
                 const float* __restrict__ Wt, const float* __restrict__ bt,
                 const float* __restrict__ Wn, const float* __restrict__ bn,
                 const float* __restrict__ Wc, const float* __restrict__ bc,
                 const float* __restrict__ Wg,
                 const float* __restrict__ att_src, const float* __restrict__ att_dst,
                 const float* __restrict__ x, const float* __restrict__ bgat,
                 const float* __restrict__ Wo1, const float* __restrict__ bo1,
                 const float* __restrict__ Wo2, const float* __restrict__ bo2,
                 const int* __restrict__ ei, int E,
                 const int* __restrict__ tgt_p,
                 int* __restrict__ done, int* __restrict__ blockCounts,
                 float* __restrict__ aS, float* __restrict__ aD,
                 float* __restrict__ h_all,
                 float* __restrict__ out) {
    __shared__ float sdes[768];
    __shared__ float stw[768];
    __shared__ float snp8[8];
    __shared__ float sfeat[FEAT];
    __shared__ float part[NT];
    __shared__ float pr[2 * HDIM];
    __shared__ int   lmatch[REG];
    __shared__ int   lcount;
    __shared__ int   sIsLast;
    // finalize scratch
    __shared__ int   sbc[NBS];
    __shared__ int   pf[NBS];
    __shared__ int   slots[NMAX];
    __shared__ float saS[NMAX * HEADS];
    __shared__ float saD[HEADS];
    __shared__ float scomb[144];
    __shared__ float shmid[64];
    __shared__ int   sM;

    const int tid = threadIdx.x;
    const int b = blockIdx.x;
    const int tgt = *tgt_p;
    const int wv = tid >> 6, lane = tid & 63;

    // ---- one node pipeline: feature -> h -> logits (uniform per block) ----
    auto process_node = [&](int node, int sid, bool isTgt) {
        if (tid < 192) {
            ((float4*)sdes)[tid] = ((const float4*)(des + (size_t)node * 768))[tid];
            ((float4*)stw)[tid]  = ((const float4*)(tw  + (size_t)node * 768))[tid];
        } else if (tid < 197) {
            snp8[tid - 192] = npr[node * 5 + (tid - 192)];
        } else if (tid == 197) {
            snp8[5] = cpr[node];
        }
        __syncthreads();

        {   // halves: [0,256) des@Wd, [256,512) tweet@Wt ; 8 chunks x 96
            const int half = tid >> 8;
            const int t2 = tid & 255;
            const int j = t2 & 31, ch = t2 >> 5;
            const float* W = half ? Wt : Wd;
            const float* S = half ? stw : sdes;
            const float* wp = W + (size_t)(ch * 96) * 32 + j;
            const float* sp = S + ch * 96;
            float p = 0.f;
            #pragma unroll 16
            for (int k = 0; k < 96; ++k) p = fmaf(sp[k], wp[(size_t)k * 32], p);
            part[tid] = p;
        }
        __syncthreads();
        if (tid < 32) {
            float a = bd[tid];
            #pragma unroll
            for (int c2 = 0; c2 < 8; ++c2) a += part[c2 * 32 + tid];
            sfeat[tid] = a > 0.f ? a : 0.01f * a;
        } else if (tid < 64) {
            const int jj = tid - 32;
            float a = bt[jj];
            #pragma unroll
            for (int c2 = 0; c2 < 8; ++c2) a += part[256 + c2 * 32 + jj];
            sfeat[32 + jj] = a > 0.f ? a : 0.01f * a;
        } else if (tid < 96) {
            const int jj = tid - 64;
            float a = bn[jj];
            #pragma unroll
            for (int k = 0; k < 5; ++k) a = fmaf(snp8[k], Wn[k * 32 + jj], a);
            sfeat[64 + jj] = a > 0.f ? a : 0.01f * a;
        } else if (tid < 128) {
            const int jj = tid - 96;
            float a = fmaf(snp8[5], Wc[jj], bc[jj]);
            sfeat[96 + jj] = a > 0.f ? a : 0.01f * a;
        }
        __syncthreads();

        {   // h = feat @ Wg : one output/thread, coalesced columns
            const float* wg = Wg + tid;
            float hv = 0.f;
            #pragma unroll 16
            for (int k = 0; k < FEAT; ++k) hv = fmaf(sfeat[k], wg[(size_t)k * HDIM], hv);
            h_all[(size_t)sid * HDIM + tid] = hv;
            pr[tid] = hv * att_src[tid];
            if (isTgt) pr[HDIM + tid] = hv * att_dst[tid];
        }
        __syncthreads();

        if (wv < 4) {
            float v = pr[wv * 128 + lane] + pr[wv * 128 + 64 + lane];
            #pragma unroll
            for (int off = 32; off > 0; off >>= 1) v += __shfl_down(v, off);
            if (lane == 0) aS[sid * HEADS + wv] = v;
        } else if (isTgt) {
            const int hd = wv - 4;
            float v = pr[HDIM + hd * 128 + lane] + pr[HDIM + hd * 128 + 64 + lane];
            #pragma unroll
            for (int off = 32; off > 0; off >>= 1) v += __shfl_down(v, off);
            if (lane == 0) aD[hd] = v;
        }
        __syncthreads();
    };

    if (b < NBS) {
        // ---- weight prefetch into L3, consumed after the scan ----
        float keep = 0.f;
        {
            const int g = b * NT + tid;
            if (g < 6144)       { float4 v = ((const float4*)Wd)[g];           keep = v.x + v.y + v.z + v.w; }
            else if (g < 12288) { float4 v = ((const float4*)Wt)[g - 6144];    keep = v.x + v.y + v.z + v.w; }
            else if (g < 28672) { float4 v = ((const float4*)Wg)[g - 12288];   keep = v.x + v.y + v.z + v.w; }
            else if (g < 30848) { float4 v = ((const float4*)Wo1)[g - 28672];  keep = v.x + v.y + v.z + v.w; }
        }

        if (tid == 0) lcount = 0;
        __syncthreads();
        const int nquad = E >> 2;
        const int qb = (nquad + NBS - 1) / NBS;
        const int q0 = b * qb;
        const int qe = (q0 + qb < nquad) ? (q0 + qb) : nquad;
        for (int q = q0 + tid; q < qe; q += NT) {
            const int4 dd = *(const int4*)(ei + (size_t)E + (size_t)q * 4);
            const int base = q * 4;
            if (dd.x == tgt) { int p = atomicAdd(&lcount, 1); if (p < REG) lmatch[p] = ei[base + 0]; }
            if (dd.y == tgt) { int p = atomicAdd(&lcount, 1); if (p < REG) lmatch[p] = ei[base + 1]; }
            if (dd.z == tgt) { int p = atomicAdd(&lcount, 1); if (p < REG) lmatch[p] = ei[base + 2]; }
            if (dd.w == tgt) { int p = atomicAdd(&lcount, 1); if (p < REG) lmatch[p] = ei[base + 3]; }
        }
        if (b == NBS - 1) {
            for (int k = nquad * 4 + tid; k < E; k += NT)
                if (ei[E + k] == tgt) { int p = atomicAdd(&lcount, 1); if (p < REG) lmatch[p] = ei[k]; }
        }
        asm volatile("" :: "v"(keep));
        __syncthreads();

        const int mycount = (lcount < REG) ? lcount : REG;
        if (tid == 0) blockCounts[b] = mycount;

        for (int it = 0; it < mycount; ++it)
            process_node(lmatch[it], b * REG + it, false);
    } else {
        // ---- dedicated target block: runs concurrently with the scan ----
        process_node(tgt, TGT_SID, true);
    }

    // ---- last-block handoff (thread-0-only release fence per block) ----
    __syncthreads();
    if (tid == 0) {
        __threadfence();                           // release: WB this XCD's dirty L2
        const int old = atomicAdd(done, 1);        // 129 blocks -> olds 0..NBS
        const int last = (old == NBS);
        if (last) __threadfence();                 // acquire: INV stale L1/L2
        sIsLast = last;
    }
    __syncthreads();
    if (!sIsLast) return;

    // ================= finalize =================
    if (tid < NBS) { sbc[tid] = blockCounts[tid]; pf[tid] = sbc[tid]; }
    __syncthreads();
    for (int off = 1; off < NBS; off <<= 1) {      // Hillis-Steele inclusive scan
        int add = (tid < NBS && tid >= off) ? pf[tid - off] : 0;
        __syncthreads();
        if (tid < NBS) pf[tid] += add;
        __syncthreads();
    }
    if (tid < NBS) {
        const int excl = pf[tid] - sbc[tid];
        for (int i = 0; i < sbc[tid]; ++i) {
            const int p = excl + i;
            if (p < NMAX - 1) slots[p] = tid * REG + i;
        }
    }
    if (tid == 0) {
        int total = pf[NBS - 1];
        if (total > NMAX - 1) total = NMAX - 1;
        slots[total] = TGT_SID;
        sM = total + 1;
    }
    __syncthreads();
    const int M = sM;

    for (int i = tid; i < M * HEADS; i += NT) {
        const int s = i >> 2, hd = i & 3;
        saS[i] = aS[slots[s] * HEADS + hd];
    }
    if (tid < HEADS) saD[tid] = aD[tid];
    __syncthreads();

    {   // softmax-weighted aggregate: one output channel/thread (512 = HDIM)
        const int o = tid, hd = o >> 7;
        const float adv = saD[hd];
        float m = -INFINITY;
        for (int s = 0; s < M; ++s) {
            float e = saS[s * HEADS + hd] + adv;
            e = e > 0.f ? e : 0.2f * e;            // leaky_relu slope 0.2
            m = fmaxf(m, e);
        }
        float denom = 0.f, acc = 0.f;
        for (int s = 0; s < M; ++s) {
            float e = saS[s * HEADS + hd] + adv;
            e = e > 0.f ? e : 0.2f * e;
            const float ex = expf(e - m);
            denom += ex;
            acc = fmaf(ex, h_all[(size_t)slots[s] * HDIM + o], acc);
        }
        pr[o] = acc / denom;
    }
    __syncthreads();

    if (tid < 128) {
        scomb[tid] = (pr[tid] + pr[128 + tid] + pr[256 + tid] + pr[384 + tid]) * 0.25f
                     + bgat[tid];
    } else if (tid < 136) {
        scomb[tid] = x[tid - 128];
    }
    __syncthreads();

    if (tid < 64) {
        float a = bo1[tid];
        #pragma unroll 8
        for (int k = 0; k < 136; ++k) a = fmaf(scomb[k], Wo1[k * 64 + tid], a);
        shmid[tid] = a > 0.f ? a : 0.f;
    }
    __syncthreads();
    if (tid < 5) {
        float a = bo2[tid];
        #pragma unroll 8
        for (int k = 0; k < 64; ++k) a = fmaf(shmid[k], Wo2[k * 5 + tid], a);
        out[tid] = a;
    }
}

extern "C" void kernel_launch(void* const* d_in, const int* in_sizes, int n_in,
                              void* d_out, int out_size, void* d_ws, size_t ws_size,
                              hipStream_t stream) {
    const float* x    = (const float*)d_in[0];
    const float* des  = (const float*)d_in[1];
    const float* tw   = (const float*)d_in[2];
    const float* npr  = (const float*)d_in[3];
    const float* cpr  = (const float*)d_in[4];
    const int*   ei   = (const int*)d_in[5];     // [2, E] flat
    const int*   tgt  = (const int*)d_in[6];
    const float* Wd   = (const float*)d_in[7];   const float* bd  = (const float*)d_in[8];
    const float* Wt   = (const float*)d_in[9];   const float* bt  = (const float*)d_in[10];
    const float* Wn   = (const float*)d_in[11];  const float* bn  = (const float*)d_in[12];
    const float* Wc   = (const float*)d_in[13];  const float* bc  = (const float*)d_in[14];
    const float* Wg   = (const float*)d_in[15];
    const float* as_  = (const float*)d_in[16];  const float* ad_ = (const float*)d_in[17];
    const float* bg   = (const float*)d_in[18];
    const float* Wo1  = (const float*)d_in[19];  const float* bo1 = (const float*)d_in[20];
    const float* Wo2  = (const float*)d_in[21];  const float* bo2 = (const float*)d_in[22];

    const int E = in_sizes[5] / 2;

    // ws: done@0 | blockCounts@256 (128 ints) | aS@1024 ((TGT_SID+1)*4 f) | aD | h_all
    char* ws = (char*)d_ws;
    int*   done        = (int*)ws;
    int*   blockCounts = (int*)(ws + 256);
    float* aS    = (float*)(ws + 1024);
    float* aD    = aS + (size_t)(TGT_SID + 1) * HEADS;
    float* h_all = aD + 16;

    zero_kernel<<<1, 64, 0, stream>>>(done);

    mega_kernel<<<NBS + 1, NT, 0, stream>>>(des, tw, npr, cpr,
                                            Wd, bd, Wt, bt, Wn, bn, Wc, bc,
                                            Wg, as_, ad_,
                                            x, bg, Wo1, bo1, Wo2, bo2,
                                            ei, E, tgt,
                                            done, blockCounts, aS, aD, h_all,
                                            (float*)d_out);
}

// Round 7
// 19.135 us; speedup vs baseline: 1.3610x; 1.3610x over previous
//
#include <hip/hip_runtime.h>
#include <math.h>

#define HEADS 4
#define CDIM 128
#define HDIM 512       // HEADS*CDIM
#define FEAT 128
#define NBS 128        // scan blocks; block NBS is the dedicated target block
#define NT 512
#define REG 8          // per-block slot region (window in-degree ~0.06)
#define TGT_SID (NBS * REG)
#define NMAX 64        // max softmax slots in finalize (incl. self-loop)

// =================== K1: scan my edge window + process my matches ===================
// Block NBS is dedicated to the target node (self-loop): starts its pipeline at t=0,
// overlapping the other blocks' edge scan. No global atomics, no fences anywhere —
// the kernel boundary publishes all plain stores (round-4/6 lesson: explicit
// device-scope fences cost more than a kernel launch gap on gfx950).
__global__ __launch_bounds__(NT)
void scan_process_kernel(const float* __restrict__ des, const float* __restrict__ tw,
                         const float* __restrict__ npr, const float* __restrict__ cpr,
                         const float* __restrict__ Wd, const float* __restrict__ bd,
                         const float* __restrict__ Wt, const float* __restrict__ bt,
                         const float* __restrict__ Wn, const float* __restrict__ bn,
                         const float* __restrict__ Wc, const float* __restrict__ bc,
                         const float* __restrict__ Wg, const float* __restrict__ Wo1,
                         const float* __restrict__ att_src, const float* __restrict__ att_dst,
                         const int* __restrict__ ei, int E,
                         const int* __restrict__ tgt_p,
                         int* __restrict__ blockCounts,
                         float* __restrict__ aS, float* __restrict__ aD,
                         float* __restrict__ h_all) {
    __shared__ float sdes[768];
    __shared__ float stw[768];
    __shared__ float snp8[8];
    __shared__ float sfeat[FEAT];
    __shared__ float part[NT];
    __shared__ float pr[2 * HDIM];
    __shared__ int   lmatch[REG];
    __shared__ int   lcount;

    const int tid = threadIdx.x;
    const int b = blockIdx.x;
    const int tgt = *tgt_p;
    const int wv = tid >> 6, lane = tid & 63;

    // ---- one node pipeline: feature -> h -> logits ----
    auto process_node = [&](int node, int sid, bool isTgt) {
        if (tid < 192) {
            ((float4*)sdes)[tid] = ((const float4*)(des + (size_t)node * 768))[tid];
            ((float4*)stw)[tid]  = ((const float4*)(tw  + (size_t)node * 768))[tid];
        } else if (tid < 197) {
            snp8[tid - 192] = npr[node * 5 + (tid - 192)];
        } else if (tid == 197) {
            snp8[5] = cpr[node];
        }
        __syncthreads();

        {   // halves: [0,256) des@Wd, [256,512) tweet@Wt ; 8 chunks x 96
            const int half = tid >> 8;
            const int t2 = tid & 255;
            const int j = t2 & 31, ch = t2 >> 5;
            const float* W = half ? Wt : Wd;
            const float* S = half ? stw : sdes;
            const float* wp = W + (size_t)(ch * 96) * 32 + j;
            const float* sp = S + ch * 96;
            float p = 0.f;
            #pragma unroll 16
            for (int k = 0; k < 96; ++k) p = fmaf(sp[k], wp[(size_t)k * 32], p);
            part[tid] = p;
        }
        __syncthreads();
        if (tid < 32) {
            float a = bd[tid];
            #pragma unroll
            for (int c2 = 0; c2 < 8; ++c2) a += part[c2 * 32 + tid];
            sfeat[tid] = a > 0.f ? a : 0.01f * a;
        } else if (tid < 64) {
            const int jj = tid - 32;
            float a = bt[jj];
            #pragma unroll
            for (int c2 = 0; c2 < 8; ++c2) a += part[256 + c2 * 32 + jj];
            sfeat[32 + jj] = a > 0.f ? a : 0.01f * a;
        } else if (tid < 96) {
            const int jj = tid - 64;
            float a = bn[jj];
            #pragma unroll
            for (int k = 0; k < 5; ++k) a = fmaf(snp8[k], Wn[k * 32 + jj], a);
            sfeat[64 + jj] = a > 0.f ? a : 0.01f * a;
        } else if (tid < 128) {
            const int jj = tid - 96;
            float a = fmaf(snp8[5], Wc[jj], bc[jj]);
            sfeat[96 + jj] = a > 0.f ? a : 0.01f * a;
        }
        __syncthreads();

        {   // h = feat @ Wg : one output/thread, coalesced columns
            const float* wg = Wg + tid;
            float hv = 0.f;
            #pragma unroll 16
            for (int k = 0; k < FEAT; ++k) hv = fmaf(sfeat[k], wg[(size_t)k * HDIM], hv);
            h_all[(size_t)sid * HDIM + tid] = hv;
            pr[tid] = hv * att_src[tid];
            if (isTgt) pr[HDIM + tid] = hv * att_dst[tid];
        }
        __syncthreads();

        if (wv < 4) {
            float v = pr[wv * 128 + lane] + pr[wv * 128 + 64 + lane];
            #pragma unroll
            for (int off = 32; off > 0; off >>= 1) v += __shfl_down(v, off);
            if (lane == 0) aS[sid * HEADS + wv] = v;
        } else if (isTgt) {
            const int hd = wv - 4;
            float v = pr[HDIM + hd * 128 + lane] + pr[HDIM + hd * 128 + 64 + lane];
            #pragma unroll
            for (int off = 32; off > 0; off >>= 1) v += __shfl_down(v, off);
            if (lane == 0) aD[hd] = v;
        }
        __syncthreads();
    };

    if (b == NBS) {
        // ---- dedicated target block: pipeline from t=0, overlapping the scan ----
        process_node(tgt, TGT_SID, true);
        return;
    }

    // ---- weight prefetch into L3 (coalesced), consumed after the scan ----
    float keep = 0.f;
    {
        const int g = b * NT + tid;
        if (g < 6144)       { float4 v = ((const float4*)Wd)[g];           keep = v.x + v.y + v.z + v.w; }
        else if (g < 12288) { float4 v = ((const float4*)Wt)[g - 6144];    keep = v.x + v.y + v.z + v.w; }
        else if (g < 28672) { float4 v = ((const float4*)Wg)[g - 12288];   keep = v.x + v.y + v.z + v.w; }
        else if (g < 30848) { float4 v = ((const float4*)Wo1)[g - 28672];  keep = v.x + v.y + v.z + v.w; }
    }

    // ---- scan my contiguous edge window (LDS-local match list) ----
    if (tid == 0) lcount = 0;
    __syncthreads();
    const int nquad = E >> 2;
    const int qb = (nquad + NBS - 1) / NBS;
    const int q0 = b * qb;
    const int qe = (q0 + qb < nquad) ? (q0 + qb) : nquad;
    for (int q = q0 + tid; q < qe; q += NT) {
        const int4 dd = *(const int4*)(ei + (size_t)E + (size_t)q * 4);
        const int base = q * 4;
        if (dd.x == tgt) { int p = atomicAdd(&lcount, 1); if (p < REG) lmatch[p] = ei[base + 0]; }
        if (dd.y == tgt) { int p = atomicAdd(&lcount, 1); if (p < REG) lmatch[p] = ei[base + 1]; }
        if (dd.z == tgt) { int p = atomicAdd(&lcount, 1); if (p < REG) lmatch[p] = ei[base + 2]; }
        if (dd.w == tgt) { int p = atomicAdd(&lcount, 1); if (p < REG) lmatch[p] = ei[base + 3]; }
    }
    if (b == NBS - 1) {
        for (int k = nquad * 4 + tid; k < E; k += NT)
            if (ei[E + k] == tgt) { int p = atomicAdd(&lcount, 1); if (p < REG) lmatch[p] = ei[k]; }
    }
    asm volatile("" :: "v"(keep));   // keep prefetch loads alive
    __syncthreads();

    const int mycount = (lcount < REG) ? lcount : REG;
    if (tid == 0) blockCounts[b] = mycount;   // plain store; kernel boundary publishes

    for (int it = 0; it < mycount; ++it)
        process_node(lmatch[it], b * REG + it, false);
}

// =================== K2: compact slots, softmax-aggregate, MLP ===================
__global__ __launch_bounds__(NT)
void finalize_kernel(const float* __restrict__ x, const float* __restrict__ bgat,
                     const float* __restrict__ Wo1, const float* __restrict__ bo1,
                     const float* __restrict__ Wo2, const float* __restrict__ bo2,
                     const int* __restrict__ blockCounts,
                     const float* __restrict__ aS, const float* __restrict__ aD,
                     const float* __restrict__ h_all,
                     float* __restrict__ out) {
    __shared__ int   bc[NBS];
    __shared__ int   pf[NBS];
    __shared__ int   slots[NMAX];
    __shared__ float saS[NMAX * HEADS];
    __shared__ float saD[HEADS];
    __shared__ float pr[HDIM];
    __shared__ float scomb[144];
    __shared__ float shmid[64];
    __shared__ int   sM;

    const int tid = threadIdx.x;

    if (tid < NBS) { bc[tid] = blockCounts[tid]; pf[tid] = bc[tid]; }
    __syncthreads();
    // Hillis-Steele inclusive scan over 128 entries (deterministic compaction)
    for (int off = 1; off < NBS; off <<= 1) {
        int add = (tid < NBS && tid >= off) ? pf[tid - off] : 0;
        __syncthreads();
        if (tid < NBS) pf[tid] += add;
        __syncthreads();
    }
    if (tid < NBS) {
        const int excl = pf[tid] - bc[tid];
        for (int i = 0; i < bc[tid]; ++i) {
            const int p = excl + i;
            if (p < NMAX - 1) slots[p] = tid * REG + i;
        }
    }
    if (tid == 0) {
        int total = pf[NBS - 1];
        if (total > NMAX - 1) total = NMAX - 1;
        slots[total] = TGT_SID;
        sM = total + 1;
    }
    __syncthreads();
    const int M = sM;

    // stage logits into LDS
    for (int i = tid; i < M * HEADS; i += NT) {
        const int s = i >> 2, hd = i & 3;
        saS[i] = aS[slots[s] * HEADS + hd];
    }
    if (tid < HEADS) saD[tid] = aD[tid];
    __syncthreads();

    // softmax-weighted aggregate: one output channel per thread (512 = HDIM)
    {
        const int o = tid, hd = o >> 7;
        const float adv = saD[hd];
        float m = -INFINITY;
        for (int s = 0; s < M; ++s) {
            float e = saS[s * HEADS + hd] + adv;
            e = e > 0.f ? e : 0.2f * e;     // leaky_relu slope 0.2
            m = fmaxf(m, e);
        }
        float denom = 0.f, acc = 0.f;
        for (int s = 0; s < M; ++s) {
            float e = saS[s * HEADS + hd] + adv;
            e = e > 0.f ? e : 0.2f * e;
            const float ex = expf(e - m);
            denom += ex;
            acc = fmaf(ex, h_all[(size_t)slots[s] * HDIM + o], acc);
        }
        pr[o] = acc / denom;
    }
    __syncthreads();

    if (tid < 128) {
        scomb[tid] = (pr[tid] + pr[128 + tid] + pr[256 + tid] + pr[384 + tid]) * 0.25f
                     + bgat[tid];
    } else if (tid < 136) {
        scomb[tid] = x[tid - 128];
    }
    __syncthreads();

    if (tid < 64) {
        float a = bo1[tid];
        #pragma unroll 8
        for (int k = 0; k < 136; ++k) a = fmaf(scomb[k], Wo1[k * 64 + tid], a);
        shmid[tid] = a > 0.f ? a : 0.f;
    }
    __syncthreads();
    if (tid < 5) {
        float a = bo2[tid];
        #pragma unroll 8
        for (int k = 0; k < 64; ++k) a = fmaf(shmid[k], Wo2[k * 5 + tid], a);
        out[tid] = a;
    }
}

extern "C" void kernel_launch(void* const* d_in, const int* in_sizes, int n_in,
                              void* d_out, int out_size, void* d_ws, size_t ws_size,
                              hipStream_t stream) {
    const float* x    = (const float*)d_in[0];
    const float* des  = (const float*)d_in[1];
    const float* tw   = (const float*)d_in[2];
    const float* npr  = (const float*)d_in[3];
    const float* cpr  = (const float*)d_in[4];
    const int*   ei   = (const int*)d_in[5];     // [2, E] flat
    const int*   tgt  = (const int*)d_in[6];
    const float* Wd   = (const float*)d_in[7];   const float* bd  = (const float*)d_in[8];
    const float* Wt   = (const float*)d_in[9];   const float* bt  = (const float*)d_in[10];
    const float* Wn   = (const float*)d_in[11];  const float* bn  = (const float*)d_in[12];
    const float* Wc   = (const float*)d_in[13];  const float* bc  = (const float*)d_in[14];
    const float* Wg   = (const float*)d_in[15];
    const float* as_  = (const float*)d_in[16];  const float* ad_ = (const float*)d_in[17];
    const float* bg   = (const float*)d_in[18];
    const float* Wo1  = (const float*)d_in[19];  const float* bo1 = (const float*)d_in[20];
    const float* Wo2  = (const float*)d_in[21];  const float* bo2 = (const float*)d_in[22];

    const int E = in_sizes[5] / 2;

    // ws: blockCounts[128] | aS[(TGT_SID+1)*4] | aD[4] | h_all[(TGT_SID+1)*512]
    char* ws = (char*)d_ws;
    int*   blockCounts = (int*)ws;
    float* aS    = (float*)(ws + 1024);
    float* aD    = aS + (size_t)(TGT_SID + 1) * HEADS;
    float* h_all = aD + 16;

    scan_process_kernel<<<NBS + 1, NT, 0, stream>>>(des, tw, npr, cpr,
                                                    Wd, bd, Wt, bt, Wn, bn, Wc, bc,
                                                    Wg, Wo1, as_, ad_,
                                                    ei, E, tgt,
                                                    blockCounts, aS, aD, h_all);

    finalize_kernel<<<1, NT, 0, stream>>>(x, bg, Wo1, bo1, Wo2, bo2,
                                          blockCounts, aS, aD, h_all, (float*)d_out);
}